// Round 5
// baseline (1531.019 us; speedup 1.0000x reference)
//
#include <hip/hip_runtime.h>

#define B_ 8
#define S_ 4096
#define H_ 768
#define C_ 64
#define NB_ 64
#define M_ (B_*S_)   // 32768 rows

#define NCH_ 8       // scan chunks
#define LCH_ 8       // blocks per chunk (NB_/NCH_)

typedef _Float16 f16x8 __attribute__((ext_vector_type(8)));
typedef _Float16 f16x4 __attribute__((ext_vector_type(4)));
typedef float    f32x4 __attribute__((ext_vector_type(4)));

// ---------------------------------------------------------------------------
// Weight transpose + f16 cast: WT[n][k] = (f16) W[k][n]
// ---------------------------------------------------------------------------
__global__ __launch_bounds__(256) void k_transpose(const float* __restrict__ src,
                                                   _Float16* __restrict__ dst) {
  __shared__ float tile[32][33];
  const int t = threadIdx.x;
  const int tx = t & 31, ty = t >> 5;              // ty 0..7
  const int n0 = blockIdx.x * 32, k0 = blockIdx.y * 32;
#pragma unroll
  for (int i = 0; i < 4; ++i)
    tile[ty + i*8][tx] = src[(k0 + ty + i*8) * H_ + n0 + tx];
  __syncthreads();
#pragma unroll
  for (int i = 0; i < 4; ++i)
    dst[(n0 + ty + i*8) * H_ + k0 + tx] = (_Float16)tile[tx][ty + i*8];
}

// ---------------------------------------------------------------------------
// Fused Q/K/V GEMM (f16 MFMA 16x16x32). Tile 64(M) x 128(N), 256 threads.
// Writes: Qb[s][h] (row-major) and KT[b][h][s], VT[b][d][s] (transposed,
// packed f16x4 along s).
// ---------------------------------------------------------------------------
__global__ __launch_bounds__(256) void k_gemm_qkv(
    const float* __restrict__ x,
    const _Float16* __restrict__ WqT, const _Float16* __restrict__ WkT,
    const _Float16* __restrict__ WvT,
    _Float16* __restrict__ Qb,
    _Float16* __restrict__ KT, _Float16* __restrict__ VT) {
  __shared__ _Float16 xs[64][40];        // [m][k]
  __shared__ _Float16 ws[3][128][40];    // [mat][n][k]
  const int t = threadIdx.x;
  const int m0 = blockIdx.x * 64, n0 = blockIdx.y * 128;
  const int lane = t & 63, wv = t >> 6;
  const int lm = lane & 15, qd = lane >> 4;
  const int sm = t >> 2, sk = (t & 3) * 8;   // x staging
  const int wn = t >> 1, wk = (t & 1) * 16;  // W staging

  f32x4 acc[3][4][2];
#pragma unroll
  for (int a = 0; a < 3; ++a)
#pragma unroll
    for (int i = 0; i < 4; ++i)
#pragma unroll
      for (int n = 0; n < 2; ++n)
        acc[a][i][n] = (f32x4){0.f, 0.f, 0.f, 0.f};

  for (int kk = 0; kk < 24; ++kk) {
    const int k0 = kk * 32;
    __syncthreads();
    { // stage x tile 64x32 (f32 -> f16)
      const f32x4* xp = (const f32x4*)&x[(size_t)(m0 + sm) * H_ + k0 + sk];
      f32x4 f0 = xp[0], f1 = xp[1];
      f16x8 xv;
#pragma unroll
      for (int j = 0; j < 4; ++j) { xv[j] = (_Float16)f0[j]; xv[4 + j] = (_Float16)f1[j]; }
      *(f16x8*)&xs[sm][sk] = xv;
    }
    { // stage 3 W tiles 128x32
      const f16x8* wp = (const f16x8*)&WqT[(n0 + wn) * H_ + k0 + wk];
      *(f16x8*)&ws[0][wn][wk] = wp[0]; *(f16x8*)&ws[0][wn][wk + 8] = wp[1];
      wp = (const f16x8*)&WkT[(n0 + wn) * H_ + k0 + wk];
      *(f16x8*)&ws[1][wn][wk] = wp[0]; *(f16x8*)&ws[1][wn][wk + 8] = wp[1];
      wp = (const f16x8*)&WvT[(n0 + wn) * H_ + k0 + wk];
      *(f16x8*)&ws[2][wn][wk] = wp[0]; *(f16x8*)&ws[2][wn][wk + 8] = wp[1];
    }
    __syncthreads();
    f16x8 af[4];
#pragma unroll
    for (int i = 0; i < 4; ++i) af[i] = *(f16x8*)&xs[i*16 + lm][qd*8];
#pragma unroll
    for (int a = 0; a < 3; ++a)
#pragma unroll
      for (int n = 0; n < 2; ++n) {
        f16x8 bfr = *(f16x8*)&ws[a][wv*32 + n*16 + lm][qd*8];
#pragma unroll
        for (int i = 0; i < 4; ++i)
          acc[a][i][n] = __builtin_amdgcn_mfma_f32_16x16x32_f16(af[i], bfr, acc[a][i][n], 0, 0, 0);
      }
  }
  // epilogue: C row=(lane>>4)*4+r (global s), col=lane&15 (global h/d)
#pragma unroll
  for (int i = 0; i < 4; ++i)
#pragma unroll
    for (int n = 0; n < 2; ++n) {
      const int ng = n0 + wv*32 + n*16 + lm;
      const int mg0 = m0 + i*16 + qd*4;
      const int bb = mg0 >> 12, ss = mg0 & (S_ - 1);
#pragma unroll
      for (int r = 0; r < 4; ++r)
        Qb[(size_t)(mg0 + r) * H_ + ng] = (_Float16)acc[0][i][n][r];
      f16x4 kp, vp;
#pragma unroll
      for (int r = 0; r < 4; ++r) {
        kp[r] = (_Float16)acc[1][i][n][r];
        vp[r] = (_Float16)acc[2][i][n][r];
      }
      *(f16x4*)&KT[((size_t)bb * H_ + ng) * S_ + ss] = kp;
      *(f16x4*)&VT[((size_t)bb * H_ + ng) * S_ + ss] = vp;
    }
}

// ---------------------------------------------------------------------------
// t = x @ W1   [32768 x 16]
// ---------------------------------------------------------------------------
__global__ __launch_bounds__(256) void k_tgemm(const float* __restrict__ x,
                                               const float* __restrict__ W1,
                                               float* __restrict__ tbuf) {
  __shared__ float w1s[768 * 16];
  __shared__ float xs[64 * 129];
  const int t = threadIdx.x;
  const int m0 = blockIdx.x * 64;
  for (int i = t; i < 768 * 16 / 4; i += 256)
    ((f32x4*)w1s)[i] = ((const f32x4*)W1)[i];
  const int row = t & 63, cg = t >> 6;
  f32x4 acc = (f32x4){0.f, 0.f, 0.f, 0.f};
  for (int kc = 0; kc < 768; kc += 128) {
    __syncthreads();
    for (int i = 0; i < 32; ++i) {
      const int idx = t + 256 * i;
      const int r = idx >> 7, c = idx & 127;
      xs[r * 129 + c] = x[(size_t)(m0 + r) * H_ + kc + c];
    }
    __syncthreads();
#pragma unroll 8
    for (int kl = 0; kl < 128; ++kl) {
      const float a = xs[row * 129 + kl];
      const f32x4 w = *(const f32x4*)&w1s[(kc + kl) * 16 + cg * 4];
#pragma unroll
      for (int j = 0; j < 4; ++j) acc[j] += a * w[j];
    }
  }
  *(f32x4*)&tbuf[(size_t)(m0 + row) * 16 + cg * 4] = acc;
}

// ---------------------------------------------------------------------------
// a[b,h] = mean_s sigmoid((t@W2)[b,s,h] + bias[h]) ^ (1/16)
// ---------------------------------------------------------------------------
__global__ __launch_bounds__(256) void k_areduce(const float* __restrict__ tbuf,
                                                 const float* __restrict__ W2,
                                                 const float* __restrict__ bias,
                                                 float* __restrict__ abuf) {
  __shared__ float ts[128 * 17];
  __shared__ float rbuf[8 * 32];
  const int t = threadIdx.x;
  const int b = blockIdx.y, hc = blockIdx.x;
  const int hl = t & 31, sg = t >> 5;
  const int h = hc * 32 + hl;
  float w2r[16];
#pragma unroll
  for (int j = 0; j < 16; ++j) w2r[j] = W2[j * H_ + h];
  const float bb = bias[h];
  float asum = 0.f;
  const float* tb = &tbuf[(size_t)(b * S_) * 16];
  for (int sc = 0; sc < S_; sc += 128) {
    __syncthreads();
    for (int i = 0; i < 8; ++i) {
      const int idx = t + 256 * i;
      const int sl = idx >> 4, j = idx & 15;
      ts[sl * 17 + j] = tb[(size_t)(sc + sl) * 16 + j];
    }
    __syncthreads();
    for (int i = 0; i < 16; ++i) {
      const int sl = sg + i * 8;
      float z = bb;
      const float* tr = &ts[sl * 17];
#pragma unroll
      for (int j = 0; j < 16; ++j) z += tr[j] * w2r[j];
      const float sgm = 1.f / (1.f + __expf(-z));
      asum += sqrtf(sqrtf(sqrtf(sqrtf(sgm))));  // ^(1/16)
    }
  }
  rbuf[sg * 32 + hl] = asum;
  __syncthreads();
  if (t < 32) {
    float s = 0.f;
#pragma unroll
    for (int g = 0; g < 8; ++g) s += rbuf[g * 32 + t];
    abuf[b * H_ + hc * 32 + t] = s * (1.f / (float)S_);
  }
}

// ---------------------------------------------------------------------------
// Per block: scores = (qb.kb^T)*tril*scale, softmax (masked zeros included),
// Y = w @ vb written to O (scan accumulates on top). grid (64 nb, 8 b).
// K and V staged from transposed KT/VT (vector loads); Q via scalar scatter.
// ---------------------------------------------------------------------------
__global__ __launch_bounds__(256) void k_scores_y(
    const _Float16* __restrict__ Qb, const _Float16* __restrict__ KT,
    const _Float16* __restrict__ VT, float* __restrict__ O) {
  __shared__ float qs[64 * 68];   // [h_local][c]
  __shared__ float ks[64 * 68];   // [h_local][d]
  __shared__ float wb[64 * 68];   // transposed: wb[d][c] = w[c][d]
  __shared__ float vsb[64 * 68];  // [j][e_local]
  const int t = threadIdx.x;
  const int nb = blockIdx.x, b = blockIdx.y;
  const size_t base = ((size_t)b * S_ + nb * 64) * H_;
  const int tc = t >> 4, td = t & 15;
  const int srow = t >> 2, sseg = (t & 3) * 16;

  float scr[4][4];
#pragma unroll
  for (int i = 0; i < 4; ++i)
#pragma unroll
    for (int u = 0; u < 4; ++u) scr[i][u] = 0.f;

  for (int hc = 0; hc < 12; ++hc) {
    __syncthreads();
    { // stage q chunk transposed -> [h][c] (scalar scatter)
      const f16x8* qp = (const f16x8*)&Qb[base + (size_t)srow * H_ + hc * 64 + sseg];
      f16x8 q0 = qp[0], q1 = qp[1];
#pragma unroll
      for (int j = 0; j < 8; ++j) {
        qs[(sseg + j) * 68 + srow] = (float)q0[j];
        qs[(sseg + 8 + j) * 68 + srow] = (float)q1[j];
      }
    }
    { // stage k chunk from KT (already [h][s]) -> vector both sides
      const size_t krow = ((size_t)b * H_ + hc * 64 + srow) * S_ + nb * 64 + sseg;
      f16x8 k0 = *(const f16x8*)&KT[krow];
      f16x8 k1 = *(const f16x8*)&KT[krow + 8];
      f32x4 f;
#pragma unroll
      for (int j = 0; j < 4; ++j) f[j] = (float)k0[j];
      *(f32x4*)&ks[srow * 68 + sseg] = f;
#pragma unroll
      for (int j = 0; j < 4; ++j) f[j] = (float)k0[4 + j];
      *(f32x4*)&ks[srow * 68 + sseg + 4] = f;
#pragma unroll
      for (int j = 0; j < 4; ++j) f[j] = (float)k1[j];
      *(f32x4*)&ks[srow * 68 + sseg + 8] = f;
#pragma unroll
      for (int j = 0; j < 4; ++j) f[j] = (float)k1[4 + j];
      *(f32x4*)&ks[srow * 68 + sseg + 12] = f;
    }
    __syncthreads();
#pragma unroll 4
    for (int h = 0; h < 64; ++h) {
      const f32x4 qv = *(f32x4*)&qs[h * 68 + tc * 4];
      const f32x4 kv = *(f32x4*)&ks[h * 68 + td * 4];
#pragma unroll
      for (int i = 0; i < 4; ++i)
#pragma unroll
        for (int u = 0; u < 4; ++u) scr[i][u] += qv[i] * kv[u];
    }
  }
  const float scale = 0.036084391824351615f;  // 1/sqrt(768)
#pragma unroll
  for (int i = 0; i < 4; ++i)
#pragma unroll
    for (int u = 0; u < 4; ++u) {
      const int c = tc * 4 + i, d = td * 4 + u;
      wb[d * 68 + c] = (d <= c) ? scr[i][u] * scale : 0.f;  // mask by multiplication
    }
  __syncthreads();
  { // softmax over 64-wide rows (zeros included), 4 threads per row
    const int r = t >> 2, g = t & 3;
    float vals[16];
    float mx = -1e30f;
#pragma unroll
    for (int i = 0; i < 16; ++i) {
      vals[i] = wb[(g * 16 + i) * 68 + r];
      mx = fmaxf(mx, vals[i]);
    }
    mx = fmaxf(mx, __shfl_xor(mx, 1));
    mx = fmaxf(mx, __shfl_xor(mx, 2));
    float sm = 0.f;
#pragma unroll
    for (int i = 0; i < 16; ++i) { vals[i] = __expf(vals[i] - mx); sm += vals[i]; }
    sm += __shfl_xor(sm, 1);
    sm += __shfl_xor(sm, 2);
    const float inv = 1.f / sm;
#pragma unroll
    for (int i = 0; i < 16; ++i) wb[(g * 16 + i) * 68 + r] = vals[i] * inv;
  }
  // Y = w @ vb  -> O (full overwrite; scan accumulates on top)
  for (int ec = 0; ec < 12; ++ec) {
    __syncthreads();
    { // stage v chunk from VT ([d][s]) -> vsb[j][e_local] (scalar scatter)
      const size_t vrow = ((size_t)b * H_ + ec * 64 + srow) * S_ + nb * 64 + sseg;
      f16x8 v0 = *(const f16x8*)&VT[vrow];
      f16x8 v1 = *(const f16x8*)&VT[vrow + 8];
#pragma unroll
      for (int j = 0; j < 8; ++j) {
        vsb[(sseg + j) * 68 + srow] = (float)v0[j];
        vsb[(sseg + 8 + j) * 68 + srow] = (float)v1[j];
      }
    }
    __syncthreads();
    float y[4][4];
#pragma unroll
    for (int i = 0; i < 4; ++i)
#pragma unroll
      for (int u = 0; u < 4; ++u) y[i][u] = 0.f;
#pragma unroll 4
    for (int j = 0; j < 64; ++j) {
      const f32x4 wv = *(f32x4*)&wb[j * 68 + tc * 4];
      const f32x4 vv = *(f32x4*)&vsb[j * 68 + td * 4];
#pragma unroll
      for (int i = 0; i < 4; ++i)
#pragma unroll
        for (int u = 0; u < 4; ++u) y[i][u] += wv[i] * vv[u];
    }
#pragma unroll
    for (int i = 0; i < 4; ++i) {
      f32x4 yv = {y[i][0], y[i][1], y[i][2], y[i][3]};
      *(f32x4*)&O[base + (size_t)(tc * 4 + i) * H_ + ec * 64 + td * 4] = yv;
    }
  }
}

// ---------------------------------------------------------------------------
// Chunk-total GEMM: T^T[d][h] = sum_{s' in chunk} a_d^{LCH-1-m(s')} V[s',d] K[s',h]
// (proven round 4). Tb layout: [b][ch][d=768][h=768] f16.
// grid x = tile*8 + ch (36 tiles of 128x128), y = b. 256 thr, 4 waves.
// ---------------------------------------------------------------------------
__global__ __launch_bounds__(256, 2) void k_chunk_gemm(
    const _Float16* __restrict__ KT, const _Float16* __restrict__ VT,
    const float* __restrict__ abuf, _Float16* __restrict__ Tb) {
  __shared__ _Float16 bs[128][40];   // K tile [h_local][s'_local], all waves
  const int t = threadIdx.x;
  const int b = blockIdx.y;
  const int ch = blockIdx.x & 7, tile = blockIdx.x >> 3;
  const int dt = tile / 6, ht = tile % 6;
  const int w = t >> 6, lane = t & 63;
  const int lm = lane & 15, qd = lane >> 4;
  const int d0 = dt * 128 + w * 32;
  const int h0 = ht * 128;
  const int hrow = t >> 1, hseg = (t & 1) * 16;

  float av[2], pw[2];
  av[0] = abuf[b * H_ + d0 + lm];
  av[1] = abuf[b * H_ + d0 + 16 + lm];
  pw[0] = 1.f; pw[1] = 1.f;

  f32x4 acc[2][8];
#pragma unroll
  for (int ds = 0; ds < 2; ++ds)
#pragma unroll
    for (int hh = 0; hh < 8; ++hh) acc[ds][hh] = (f32x4){0.f, 0.f, 0.f, 0.f};

  const size_t ktb = (size_t)b * H_ * S_;
  for (int kk = 15; kk >= 0; --kk) {
    const int sp = ch * 512 + kk * 32;
    __syncthreads();
    { // stage K tile [128 h][32 s'] (KT rows are contiguous in s)
      const f16x8* kp = (const f16x8*)&KT[ktb + (size_t)(h0 + hrow) * S_ + sp + hseg];
      *(f16x8*)&bs[hrow][hseg] = kp[0];
      *(f16x8*)&bs[hrow][hseg + 8] = kp[1];
    }
    __syncthreads();
    f16x8 va0 = *(const f16x8*)&VT[ktb + (size_t)(d0 + lm) * S_ + sp + qd * 8];
    f16x8 va1 = *(const f16x8*)&VT[ktb + (size_t)(d0 + 16 + lm) * S_ + sp + qd * 8];
    va0 *= (_Float16)pw[0];
    va1 *= (_Float16)pw[1];
#pragma unroll
    for (int hh = 0; hh < 8; ++hh) {
      const f16x8 kf = *(const f16x8*)&bs[hh * 16 + lm][qd * 8];
      acc[0][hh] = __builtin_amdgcn_mfma_f32_16x16x32_f16(va0, kf, acc[0][hh], 0, 0, 0);
      acc[1][hh] = __builtin_amdgcn_mfma_f32_16x16x32_f16(va1, kf, acc[1][hh], 0, 0, 0);
    }
    if (!(kk & 1)) { pw[0] *= av[0]; pw[1] *= av[1]; }
  }
  // store T^T[d][h]: C row=(lane>>4)*4+r -> d_local, col=lane&15 -> h_local
  _Float16* tp = Tb + (size_t)(b * NCH_ + ch) * 768 * 768;
#pragma unroll
  for (int ds = 0; ds < 2; ++ds)
#pragma unroll
    for (int hh = 0; hh < 8; ++hh)
#pragma unroll
      for (int r = 0; r < 4; ++r)
        tp[(size_t)(d0 + ds * 16 + qd * 4 + r) * 768 + h0 + hh * 16 + lm] =
            (_Float16)acc[ds][hh][r];
}

// ---------------------------------------------------------------------------
// Chunk-carry combine (in place): Cin_0 = 0; Cin_p = a^LCH * Cin_{p-1} + T_{p-1}.
// Each thread owns one f16x8 strip (8 h) across all chunks, carry in f32.
// grid 2304 x 256 = 8b * 24dt * 32dl * 96hv threads. (proven)
// ---------------------------------------------------------------------------
__global__ __launch_bounds__(256) void k_combine(const float* __restrict__ abuf,
                                                 _Float16* __restrict__ Tb) {
  const int gid = blockIdx.x * 256 + threadIdx.x;
  const int hv = gid % 96;
  const int dl = (gid / 96) & 31;
  const int dt = (gid / (96 * 32)) % 24;
  const int b  = gid / (96 * 32 * 24);
  const float ad = abuf[b * H_ + dt * 32 + dl];
  const float a2 = ad * ad, a4 = a2 * a2;
  const float aL = a4 * a4;  // a^8 == a^LCH_
  float carry[8];
#pragma unroll
  for (int j = 0; j < 8; ++j) carry[j] = 0.f;
  const size_t chstride = (size_t)24 * 32 * 768;
  _Float16* p = Tb + (size_t)b * NCH_ * chstride + ((size_t)dt * 32 + dl) * 768 + hv * 8;
  for (int ch = 0; ch < NCH_; ++ch, p += chstride) {
    const f16x8 tv = *(const f16x8*)p;
    f16x8 cv;
#pragma unroll
    for (int j = 0; j < 8; ++j) {
      cv[j] = (_Float16)carry[j];
      carry[j] = carry[j] * aL + (float)tv[j];
    }
    *(f16x8*)p = cv;
  }
}

// ---------------------------------------------------------------------------
// Chunked scan phase 3, d-tile 16 (occupancy fix): init state from Cin (Tb
// after combine), rescan the chunk's LCH_ blocks recomputing updates, and emit
// O += Q.St per step. acc = 12 f32x4 (48 AGPR, was 96) -> 3 waves/SIMD.
// grid (48 dt, NCH_ ch, 8 b), 256 threads (4 waves).
// ---------------------------------------------------------------------------
#define STP 776  // StL h-stride (halves): 16B aligned, 2-way-free banks
__global__ __launch_bounds__(256, 3) void k_scan_out(
    const _Float16* __restrict__ Qb, const _Float16* __restrict__ KT,
    const _Float16* __restrict__ VT, const float* __restrict__ abuf,
    const _Float16* __restrict__ Tb, float* __restrict__ O) {
  __shared__ _Float16 StL[16 * STP];
  const int t = threadIdx.x;
  const int b = blockIdx.z, ch = blockIdx.y, dt = blockIdx.x;
  const int d0 = dt * 16;
  const int w = t >> 6, lane = t & 63;
  const int lm = lane & 15, qd = lane >> 4;

  const float av0 = abuf[b * H_ + d0 + lm];

  // init state from carry-in (Tb[d][h], rows d0..d0+15)
  f32x4 acc[12];
  {
    const _Float16* tp = Tb + (size_t)(b * NCH_ + ch) * 768 * 768 + (size_t)d0 * 768;
#pragma unroll
    for (int mt = 0; mt < 12; ++mt) {
      const int h = (w * 12 + mt) * 16 + qd * 4;
      const f16x4 c0 = *(const f16x4*)&tp[(size_t)lm * 768 + h];
#pragma unroll
      for (int r = 0; r < 4; ++r) acc[mt][r] = (float)c0[r];
    }
  }

  const size_t ktb = (size_t)b * H_ * S_;
  const size_t vrow0 = ktb + (size_t)(d0 + lm) * S_;

  for (int blk = ch * LCH_; blk < ch * LCH_ + LCH_; ++blk) {
    const int s0 = blk * 64;
    // ---- update: St = St*a + K^T V ----
    f16x8 vf00 = *(const f16x8*)&VT[vrow0 + s0 + qd * 8];
    f16x8 vf01 = *(const f16x8*)&VT[vrow0 + s0 + 32 + qd * 8];
#pragma unroll
    for (int mt = 0; mt < 12; ++mt) {
      const size_t arow = ktb + (size_t)((w * 12 + mt) * 16 + lm) * S_ + s0 + qd * 8;
      f16x8 a0 = *(const f16x8*)&KT[arow];
      f16x8 a1 = *(const f16x8*)&KT[arow + 32];
      f32x4 c0 = acc[mt] * av0;
      c0 = __builtin_amdgcn_mfma_f32_16x16x32_f16(a0, vf00, c0, 0, 0, 0);
      c0 = __builtin_amdgcn_mfma_f32_16x16x32_f16(a1, vf01, c0, 0, 0, 0);
      acc[mt] = c0;
    }
    __syncthreads();   // previous step's StL readers done
    // ---- St -> LDS f16, layout StL[d][h] ----
#pragma unroll
    for (int mt = 0; mt < 12; ++mt) {
      const int h = (w * 12 + mt) * 16 + qd * 4;
      f16x4 p0;
#pragma unroll
      for (int r = 0; r < 4; ++r) p0[r] = (_Float16)acc[mt][r];
      *(f16x4*)&StL[lm * STP + h] = p0;
    }
    __syncthreads();
    // ---- output: O += Q . St (wave w owns rows s0 + w*16 .. +15) ----
    f32x4 o0a = {0.f,0.f,0.f,0.f}, o0b = {0.f,0.f,0.f,0.f};
    const size_t qrow = ((size_t)b * S_ + s0 + w * 16 + lm) * H_ + qd * 8;
#pragma unroll 6
    for (int kt = 0; kt < 24; kt += 2) {
      f16x8 qa = *(const f16x8*)&Qb[qrow + kt * 32];
      f16x8 qb2 = *(const f16x8*)&Qb[qrow + kt * 32 + 32];
      f16x8 s00 = *(f16x8*)&StL[lm * STP + kt * 32 + qd * 8];
      f16x8 s10 = *(f16x8*)&StL[lm * STP + kt * 32 + 32 + qd * 8];
      o0a = __builtin_amdgcn_mfma_f32_16x16x32_f16(qa, s00, o0a, 0, 0, 0);
      o0b = __builtin_amdgcn_mfma_f32_16x16x32_f16(qb2, s10, o0b, 0, 0, 0);
    }
    const f32x4 o0 = o0a + o0b;
    const size_t orow = ((size_t)b * S_ + s0 + w * 16 + qd * 4) * H_ + d0;
#pragma unroll
    for (int r = 0; r < 4; ++r)
      O[orow + (size_t)r * H_ + lm] += o0[r];
  }
}

// ---------------------------------------------------------------------------
extern "C" void kernel_launch(void* const* d_in, const int* in_sizes, int n_in,
                              void* d_out, int out_size, void* d_ws, size_t ws_size,
                              hipStream_t stream) {
  (void)in_sizes; (void)n_in; (void)out_size; (void)ws_size;
  const float* x    = (const float*)d_in[0];
  const float* Wq   = (const float*)d_in[1];
  const float* Wk   = (const float*)d_in[2];
  const float* Wv   = (const float*)d_in[3];
  const float* W1   = (const float*)d_in[4];
  const float* W2   = (const float*)d_in[5];
  const float* bias = (const float*)d_in[6];
  float* O = (float*)d_out;

  // workspace (~221 MiB; proven available >= ~307 MiB):
  // Qb row-major f16; KT,VT transposed f16; weightsT; tbuf; abuf; Tb
  char* ws = (char*)d_ws;
  _Float16* Qb  = (_Float16*)ws;
  _Float16* KT  = Qb + (size_t)M_ * H_;
  _Float16* VT  = KT + (size_t)M_ * H_;
  _Float16* WqT = VT + (size_t)M_ * H_;
  _Float16* WkT = WqT + H_ * H_;
  _Float16* WvT = WkT + H_ * H_;
  float* tbuf = (float*)(WvT + H_ * H_);
  float* abuf = tbuf + (size_t)M_ * 16;
  _Float16* Tb = (_Float16*)(abuf + B_ * H_);   // [b][ch][d=768][h=768]

  k_transpose<<<dim3(24, 24), 256, 0, stream>>>(Wq, WqT);
  k_transpose<<<dim3(24, 24), 256, 0, stream>>>(Wk, WkT);
  k_transpose<<<dim3(24, 24), 256, 0, stream>>>(Wv, WvT);
  k_tgemm<<<dim3(512), 256, 0, stream>>>(x, W1, tbuf);
  k_areduce<<<dim3(24, 8), 256, 0, stream>>>(tbuf, W2, bias, abuf);
  k_gemm_qkv<<<dim3(512, 6), 256, 0, stream>>>(x, WqT, WkT, WvT, Qb, KT, VT);
  k_scores_y<<<dim3(64, 8), 256, 0, stream>>>(Qb, KT, VT, O);
  k_chunk_gemm<<<dim3(288, 8), 256, 0, stream>>>(KT, VT, abuf, Tb);
  k_combine<<<dim3(2304), 256, 0, stream>>>(abuf, Tb);
  k_scan_out<<<dim3(48, NCH_, 8), 256, 0, stream>>>(Qb, KT, VT, abuf, Tb, O);
}

// Round 6
// 1290.088 us; speedup vs baseline: 1.1868x; 1.1868x over previous
//
#include <hip/hip_runtime.h>

#define B_ 8
#define S_ 4096
#define H_ 768
#define C_ 64
#define NB_ 64
#define M_ (B_*S_)   // 32768 rows

#define NCH_ 8       // scan chunks
#define LCH_ 8       // blocks per chunk (NB_/NCH_)

typedef _Float16 f16x8 __attribute__((ext_vector_type(8)));
typedef _Float16 f16x4 __attribute__((ext_vector_type(4)));
typedef float    f32x4 __attribute__((ext_vector_type(4)));

// ---------------------------------------------------------------------------
// Weight transpose + f16 cast: WT[n][k] = (f16) W[k][n]
// ---------------------------------------------------------------------------
__global__ __launch_bounds__(256) void k_transpose(const float* __restrict__ src,
                                                   _Float16* __restrict__ dst) {
  __shared__ float tile[32][33];
  const int t = threadIdx.x;
  const int tx = t & 31, ty = t >> 5;              // ty 0..7
  const int n0 = blockIdx.x * 32, k0 = blockIdx.y * 32;
#pragma unroll
  for (int i = 0; i < 4; ++i)
    tile[ty + i*8][tx] = src[(k0 + ty + i*8) * H_ + n0 + tx];
  __syncthreads();
#pragma unroll
  for (int i = 0; i < 4; ++i)
    dst[(n0 + ty + i*8) * H_ + k0 + tx] = (_Float16)tile[tx][ty + i*8];
}

// ---------------------------------------------------------------------------
// Fused Q/K/V GEMM (f16 MFMA 16x16x32). Tile 64(M) x 128(N), 256 threads.
// Writes: Qb[s][h] (row-major) and KT[b][h][s], VT[b][d][s] (transposed,
// packed f16x4 along s).
// ---------------------------------------------------------------------------
__global__ __launch_bounds__(256) void k_gemm_qkv(
    const float* __restrict__ x,
    const _Float16* __restrict__ WqT, const _Float16* __restrict__ WkT,
    const _Float16* __restrict__ WvT,
    _Float16* __restrict__ Qb,
    _Float16* __restrict__ KT, _Float16* __restrict__ VT) {
  __shared__ _Float16 xs[64][40];        // [m][k]
  __shared__ _Float16 ws[3][128][40];    // [mat][n][k]
  const int t = threadIdx.x;
  const int m0 = blockIdx.x * 64, n0 = blockIdx.y * 128;
  const int lane = t & 63, wv = t >> 6;
  const int lm = lane & 15, qd = lane >> 4;
  const int sm = t >> 2, sk = (t & 3) * 8;   // x staging
  const int wn = t >> 1, wk = (t & 1) * 16;  // W staging

  f32x4 acc[3][4][2];
#pragma unroll
  for (int a = 0; a < 3; ++a)
#pragma unroll
    for (int i = 0; i < 4; ++i)
#pragma unroll
      for (int n = 0; n < 2; ++n)
        acc[a][i][n] = (f32x4){0.f, 0.f, 0.f, 0.f};

  for (int kk = 0; kk < 24; ++kk) {
    const int k0 = kk * 32;
    __syncthreads();
    { // stage x tile 64x32 (f32 -> f16)
      const f32x4* xp = (const f32x4*)&x[(size_t)(m0 + sm) * H_ + k0 + sk];
      f32x4 f0 = xp[0], f1 = xp[1];
      f16x8 xv;
#pragma unroll
      for (int j = 0; j < 4; ++j) { xv[j] = (_Float16)f0[j]; xv[4 + j] = (_Float16)f1[j]; }
      *(f16x8*)&xs[sm][sk] = xv;
    }
    { // stage 3 W tiles 128x32
      const f16x8* wp = (const f16x8*)&WqT[(n0 + wn) * H_ + k0 + wk];
      *(f16x8*)&ws[0][wn][wk] = wp[0]; *(f16x8*)&ws[0][wn][wk + 8] = wp[1];
      wp = (const f16x8*)&WkT[(n0 + wn) * H_ + k0 + wk];
      *(f16x8*)&ws[1][wn][wk] = wp[0]; *(f16x8*)&ws[1][wn][wk + 8] = wp[1];
      wp = (const f16x8*)&WvT[(n0 + wn) * H_ + k0 + wk];
      *(f16x8*)&ws[2][wn][wk] = wp[0]; *(f16x8*)&ws[2][wn][wk + 8] = wp[1];
    }
    __syncthreads();
    f16x8 af[4];
#pragma unroll
    for (int i = 0; i < 4; ++i) af[i] = *(f16x8*)&xs[i*16 + lm][qd*8];
#pragma unroll
    for (int a = 0; a < 3; ++a)
#pragma unroll
      for (int n = 0; n < 2; ++n) {
        f16x8 bfr = *(f16x8*)&ws[a][wv*32 + n*16 + lm][qd*8];
#pragma unroll
        for (int i = 0; i < 4; ++i)
          acc[a][i][n] = __builtin_amdgcn_mfma_f32_16x16x32_f16(af[i], bfr, acc[a][i][n], 0, 0, 0);
      }
  }
  // epilogue: C row=(lane>>4)*4+r (global s), col=lane&15 (global h/d)
#pragma unroll
  for (int i = 0; i < 4; ++i)
#pragma unroll
    for (int n = 0; n < 2; ++n) {
      const int ng = n0 + wv*32 + n*16 + lm;
      const int mg0 = m0 + i*16 + qd*4;
      const int bb = mg0 >> 12, ss = mg0 & (S_ - 1);
#pragma unroll
      for (int r = 0; r < 4; ++r)
        Qb[(size_t)(mg0 + r) * H_ + ng] = (_Float16)acc[0][i][n][r];
      f16x4 kp, vp;
#pragma unroll
      for (int r = 0; r < 4; ++r) {
        kp[r] = (_Float16)acc[1][i][n][r];
        vp[r] = (_Float16)acc[2][i][n][r];
      }
      *(f16x4*)&KT[((size_t)bb * H_ + ng) * S_ + ss] = kp;
      *(f16x4*)&VT[((size_t)bb * H_ + ng) * S_ + ss] = vp;
    }
}

// ---------------------------------------------------------------------------
// t = x @ W1   [32768 x 16]
// ---------------------------------------------------------------------------
__global__ __launch_bounds__(256) void k_tgemm(const float* __restrict__ x,
                                               const float* __restrict__ W1,
                                               float* __restrict__ tbuf) {
  __shared__ float w1s[768 * 16];
  __shared__ float xs[64 * 129];
  const int t = threadIdx.x;
  const int m0 = blockIdx.x * 64;
  for (int i = t; i < 768 * 16 / 4; i += 256)
    ((f32x4*)w1s)[i] = ((const f32x4*)W1)[i];
  const int row = t & 63, cg = t >> 6;
  f32x4 acc = (f32x4){0.f, 0.f, 0.f, 0.f};
  for (int kc = 0; kc < 768; kc += 128) {
    __syncthreads();
    for (int i = 0; i < 32; ++i) {
      const int idx = t + 256 * i;
      const int r = idx >> 7, c = idx & 127;
      xs[r * 129 + c] = x[(size_t)(m0 + r) * H_ + kc + c];
    }
    __syncthreads();
#pragma unroll 8
    for (int kl = 0; kl < 128; ++kl) {
      const float a = xs[row * 129 + kl];
      const f32x4 w = *(const f32x4*)&w1s[(kc + kl) * 16 + cg * 4];
#pragma unroll
      for (int j = 0; j < 4; ++j) acc[j] += a * w[j];
    }
  }
  *(f32x4*)&tbuf[(size_t)(m0 + row) * 16 + cg * 4] = acc;
}

// ---------------------------------------------------------------------------
// a[b,h] = mean_s sigmoid((t@W2)[b,s,h] + bias[h]) ^ (1/16)
// ---------------------------------------------------------------------------
__global__ __launch_bounds__(256) void k_areduce(const float* __restrict__ tbuf,
                                                 const float* __restrict__ W2,
                                                 const float* __restrict__ bias,
                                                 float* __restrict__ abuf) {
  __shared__ float ts[128 * 17];
  __shared__ float rbuf[8 * 32];
  const int t = threadIdx.x;
  const int b = blockIdx.y, hc = blockIdx.x;
  const int hl = t & 31, sg = t >> 5;
  const int h = hc * 32 + hl;
  float w2r[16];
#pragma unroll
  for (int j = 0; j < 16; ++j) w2r[j] = W2[j * H_ + h];
  const float bb = bias[h];
  float asum = 0.f;
  const float* tb = &tbuf[(size_t)(b * S_) * 16];
  for (int sc = 0; sc < S_; sc += 128) {
    __syncthreads();
    for (int i = 0; i < 8; ++i) {
      const int idx = t + 256 * i;
      const int sl = idx >> 4, j = idx & 15;
      ts[sl * 17 + j] = tb[(size_t)(sc + sl) * 16 + j];
    }
    __syncthreads();
    for (int i = 0; i < 16; ++i) {
      const int sl = sg + i * 8;
      float z = bb;
      const float* tr = &ts[sl * 17];
#pragma unroll
      for (int j = 0; j < 16; ++j) z += tr[j] * w2r[j];
      const float sgm = 1.f / (1.f + __expf(-z));
      asum += sqrtf(sqrtf(sqrtf(sqrtf(sgm))));  // ^(1/16)
    }
  }
  rbuf[sg * 32 + hl] = asum;
  __syncthreads();
  if (t < 32) {
    float s = 0.f;
#pragma unroll
    for (int g = 0; g < 8; ++g) s += rbuf[g * 32 + t];
    abuf[b * H_ + hc * 32 + t] = s * (1.f / (float)S_);
  }
}

// ---------------------------------------------------------------------------
// Per block: scores = (qb.kb^T)*tril*scale, softmax (masked zeros included),
// Y = w @ vb written to O (scan accumulates on top). grid (64 nb, 8 b).
// K and V staged from transposed KT/VT (vector loads); Q via scalar scatter.
// ---------------------------------------------------------------------------
__global__ __launch_bounds__(256) void k_scores_y(
    const _Float16* __restrict__ Qb, const _Float16* __restrict__ KT,
    const _Float16* __restrict__ VT, float* __restrict__ O) {
  __shared__ float qs[64 * 68];   // [h_local][c]
  __shared__ float ks[64 * 68];   // [h_local][d]
  __shared__ float wb[64 * 68];   // transposed: wb[d][c] = w[c][d]
  __shared__ float vsb[64 * 68];  // [j][e_local]
  const int t = threadIdx.x;
  const int nb = blockIdx.x, b = blockIdx.y;
  const size_t base = ((size_t)b * S_ + nb * 64) * H_;
  const int tc = t >> 4, td = t & 15;
  const int srow = t >> 2, sseg = (t & 3) * 16;

  float scr[4][4];
#pragma unroll
  for (int i = 0; i < 4; ++i)
#pragma unroll
    for (int u = 0; u < 4; ++u) scr[i][u] = 0.f;

  for (int hc = 0; hc < 12; ++hc) {
    __syncthreads();
    { // stage q chunk transposed -> [h][c] (scalar scatter)
      const f16x8* qp = (const f16x8*)&Qb[base + (size_t)srow * H_ + hc * 64 + sseg];
      f16x8 q0 = qp[0], q1 = qp[1];
#pragma unroll
      for (int j = 0; j < 8; ++j) {
        qs[(sseg + j) * 68 + srow] = (float)q0[j];
        qs[(sseg + 8 + j) * 68 + srow] = (float)q1[j];
      }
    }
    { // stage k chunk from KT (already [h][s]) -> vector both sides
      const size_t krow = ((size_t)b * H_ + hc * 64 + srow) * S_ + nb * 64 + sseg;
      f16x8 k0 = *(const f16x8*)&KT[krow];
      f16x8 k1 = *(const f16x8*)&KT[krow + 8];
      f32x4 f;
#pragma unroll
      for (int j = 0; j < 4; ++j) f[j] = (float)k0[j];
      *(f32x4*)&ks[srow * 68 + sseg] = f;
#pragma unroll
      for (int j = 0; j < 4; ++j) f[j] = (float)k0[4 + j];
      *(f32x4*)&ks[srow * 68 + sseg + 4] = f;
#pragma unroll
      for (int j = 0; j < 4; ++j) f[j] = (float)k1[j];
      *(f32x4*)&ks[srow * 68 + sseg + 8] = f;
#pragma unroll
      for (int j = 0; j < 4; ++j) f[j] = (float)k1[4 + j];
      *(f32x4*)&ks[srow * 68 + sseg + 12] = f;
    }
    __syncthreads();
#pragma unroll 4
    for (int h = 0; h < 64; ++h) {
      const f32x4 qv = *(f32x4*)&qs[h * 68 + tc * 4];
      const f32x4 kv = *(f32x4*)&ks[h * 68 + td * 4];
#pragma unroll
      for (int i = 0; i < 4; ++i)
#pragma unroll
        for (int u = 0; u < 4; ++u) scr[i][u] += qv[i] * kv[u];
    }
  }
  const float scale = 0.036084391824351615f;  // 1/sqrt(768)
#pragma unroll
  for (int i = 0; i < 4; ++i)
#pragma unroll
    for (int u = 0; u < 4; ++u) {
      const int c = tc * 4 + i, d = td * 4 + u;
      wb[d * 68 + c] = (d <= c) ? scr[i][u] * scale : 0.f;  // mask by multiplication
    }
  __syncthreads();
  { // softmax over 64-wide rows (zeros included), 4 threads per row
    const int r = t >> 2, g = t & 3;
    float vals[16];
    float mx = -1e30f;
#pragma unroll
    for (int i = 0; i < 16; ++i) {
      vals[i] = wb[(g * 16 + i) * 68 + r];
      mx = fmaxf(mx, vals[i]);
    }
    mx = fmaxf(mx, __shfl_xor(mx, 1));
    mx = fmaxf(mx, __shfl_xor(mx, 2));
    float sm = 0.f;
#pragma unroll
    for (int i = 0; i < 16; ++i) { vals[i] = __expf(vals[i] - mx); sm += vals[i]; }
    sm += __shfl_xor(sm, 1);
    sm += __shfl_xor(sm, 2);
    const float inv = 1.f / sm;
#pragma unroll
    for (int i = 0; i < 16; ++i) wb[(g * 16 + i) * 68 + r] = vals[i] * inv;
  }
  // Y = w @ vb  -> O (full overwrite; scan accumulates on top)
  for (int ec = 0; ec < 12; ++ec) {
    __syncthreads();
    { // stage v chunk from VT ([d][s]) -> vsb[j][e_local] (scalar scatter)
      const size_t vrow = ((size_t)b * H_ + ec * 64 + srow) * S_ + nb * 64 + sseg;
      f16x8 v0 = *(const f16x8*)&VT[vrow];
      f16x8 v1 = *(const f16x8*)&VT[vrow + 8];
#pragma unroll
      for (int j = 0; j < 8; ++j) {
        vsb[(sseg + j) * 68 + srow] = (float)v0[j];
        vsb[(sseg + 8 + j) * 68 + srow] = (float)v1[j];
      }
    }
    __syncthreads();
    float y[4][4];
#pragma unroll
    for (int i = 0; i < 4; ++i)
#pragma unroll
      for (int u = 0; u < 4; ++u) y[i][u] = 0.f;
#pragma unroll 4
    for (int j = 0; j < 64; ++j) {
      const f32x4 wv = *(f32x4*)&wb[j * 68 + tc * 4];
      const f32x4 vv = *(f32x4*)&vsb[j * 68 + td * 4];
#pragma unroll
      for (int i = 0; i < 4; ++i)
#pragma unroll
        for (int u = 0; u < 4; ++u) y[i][u] += wv[i] * vv[u];
    }
#pragma unroll
    for (int i = 0; i < 4; ++i) {
      f32x4 yv = {y[i][0], y[i][1], y[i][2], y[i][3]};
      *(f32x4*)&O[base + (size_t)(tc * 4 + i) * H_ + ec * 64 + td * 4] = yv;
    }
  }
}

// ---------------------------------------------------------------------------
// Chunk-total GEMM: T^T[d][h] = sum_{s' in chunk} a_d^{LCH-1-m(s')} V[s',d] K[s',h]
// (proven round 4). Tb layout: [b][ch][d=768][h=768] f16.
// grid x = tile*8 + ch (36 tiles of 128x128), y = b. 256 thr, 4 waves.
// ---------------------------------------------------------------------------
__global__ __launch_bounds__(256, 2) void k_chunk_gemm(
    const _Float16* __restrict__ KT, const _Float16* __restrict__ VT,
    const float* __restrict__ abuf, _Float16* __restrict__ Tb) {
  __shared__ _Float16 bs[128][40];   // K tile [h_local][s'_local], all waves
  const int t = threadIdx.x;
  const int b = blockIdx.y;
  const int ch = blockIdx.x & 7, tile = blockIdx.x >> 3;
  const int dt = tile / 6, ht = tile % 6;
  const int w = t >> 6, lane = t & 63;
  const int lm = lane & 15, qd = lane >> 4;
  const int d0 = dt * 128 + w * 32;
  const int h0 = ht * 128;
  const int hrow = t >> 1, hseg = (t & 1) * 16;

  float av[2], pw[2];
  av[0] = abuf[b * H_ + d0 + lm];
  av[1] = abuf[b * H_ + d0 + 16 + lm];
  pw[0] = 1.f; pw[1] = 1.f;

  f32x4 acc[2][8];
#pragma unroll
  for (int ds = 0; ds < 2; ++ds)
#pragma unroll
    for (int hh = 0; hh < 8; ++hh) acc[ds][hh] = (f32x4){0.f, 0.f, 0.f, 0.f};

  const size_t ktb = (size_t)b * H_ * S_;
  for (int kk = 15; kk >= 0; --kk) {
    const int sp = ch * 512 + kk * 32;
    __syncthreads();
    { // stage K tile [128 h][32 s'] (KT rows are contiguous in s)
      const f16x8* kp = (const f16x8*)&KT[ktb + (size_t)(h0 + hrow) * S_ + sp + hseg];
      *(f16x8*)&bs[hrow][hseg] = kp[0];
      *(f16x8*)&bs[hrow][hseg + 8] = kp[1];
    }
    __syncthreads();
    f16x8 va0 = *(const f16x8*)&VT[ktb + (size_t)(d0 + lm) * S_ + sp + qd * 8];
    f16x8 va1 = *(const f16x8*)&VT[ktb + (size_t)(d0 + 16 + lm) * S_ + sp + qd * 8];
    va0 *= (_Float16)pw[0];
    va1 *= (_Float16)pw[1];
#pragma unroll
    for (int hh = 0; hh < 8; ++hh) {
      const f16x8 kf = *(const f16x8*)&bs[hh * 16 + lm][qd * 8];
      acc[0][hh] = __builtin_amdgcn_mfma_f32_16x16x32_f16(va0, kf, acc[0][hh], 0, 0, 0);
      acc[1][hh] = __builtin_amdgcn_mfma_f32_16x16x32_f16(va1, kf, acc[1][hh], 0, 0, 0);
    }
    if (!(kk & 1)) { pw[0] *= av[0]; pw[1] *= av[1]; }
  }
  // store T^T[d][h]: C row=(lane>>4)*4+r -> d_local, col=lane&15 -> h_local
  _Float16* tp = Tb + (size_t)(b * NCH_ + ch) * 768 * 768;
#pragma unroll
  for (int ds = 0; ds < 2; ++ds)
#pragma unroll
    for (int hh = 0; hh < 8; ++hh)
#pragma unroll
      for (int r = 0; r < 4; ++r)
        tp[(size_t)(d0 + ds * 16 + qd * 4 + r) * 768 + h0 + hh * 16 + lm] =
            (_Float16)acc[ds][hh][r];
}

// ---------------------------------------------------------------------------
// Chunk-carry combine (in place): Cin_0 = 0; Cin_p = a^LCH * Cin_{p-1} + T_{p-1}.
// Each thread owns one f16x8 strip (8 h) across all chunks, carry in f32.
// grid 2304 x 256 = 8b * 24dt * 32dl * 96hv threads. (proven)
// ---------------------------------------------------------------------------
__global__ __launch_bounds__(256) void k_combine(const float* __restrict__ abuf,
                                                 _Float16* __restrict__ Tb) {
  const int gid = blockIdx.x * 256 + threadIdx.x;
  const int hv = gid % 96;
  const int dl = (gid / 96) & 31;
  const int dt = (gid / (96 * 32)) % 24;
  const int b  = gid / (96 * 32 * 24);
  const float ad = abuf[b * H_ + dt * 32 + dl];
  const float a2 = ad * ad, a4 = a2 * a2;
  const float aL = a4 * a4;  // a^8 == a^LCH_
  float carry[8];
#pragma unroll
  for (int j = 0; j < 8; ++j) carry[j] = 0.f;
  const size_t chstride = (size_t)24 * 32 * 768;
  _Float16* p = Tb + (size_t)b * NCH_ * chstride + ((size_t)dt * 32 + dl) * 768 + hv * 8;
  for (int ch = 0; ch < NCH_; ++ch, p += chstride) {
    const f16x8 tv = *(const f16x8*)p;
    f16x8 cv;
#pragma unroll
    for (int j = 0; j < 8; ++j) {
      cv[j] = (_Float16)carry[j];
      carry[j] = carry[j] * aL + (float)tv[j];
    }
    *(f16x8*)p = cv;
  }
}

// ---------------------------------------------------------------------------
// Chunked scan phase 3 (round-4 proven body, d-tile 32) + XCD-grouping
// swizzle: the 24 dt-blocks of each (ch,b) group get linear IDs congruent
// mod 8, so (under round-robin dispatch) they share one XCD's L2 and the
// group's K/Q/V/Tb working set (~2.3 MB < 4 MB L2) is fetched once.
// grid flat 1536, 256 threads (4 waves).
// ---------------------------------------------------------------------------
#define STP 776  // StL h-stride (halves): 16B aligned, 2-way-free banks
__global__ __launch_bounds__(256, 2) void k_scan_out(
    const _Float16* __restrict__ Qb, const _Float16* __restrict__ KT,
    const _Float16* __restrict__ VT, const float* __restrict__ abuf,
    const _Float16* __restrict__ Tb, float* __restrict__ O) {
  __shared__ _Float16 StL[32 * STP];
  const int t = threadIdx.x;
  // XCD-group decode: lin%8 = xcd slot; groups g=(j/24)*8+xcd, dt=j%24
  const int lin = blockIdx.x;
  const int xcd = lin & 7, j = lin >> 3;
  const int g = (j / 24) * 8 + xcd;           // 0..63 = (b,ch) group
  const int dt = j % 24;
  const int ch = g & 7, b = g >> 3;
  const int d0 = dt * 32;
  const int w = t >> 6, lane = t & 63;
  const int lm = lane & 15, qd = lane >> 4;

  const float av0 = abuf[b * H_ + d0 + lm];
  const float av1 = abuf[b * H_ + d0 + 16 + lm];

  // init state from carry-in
  f32x4 acc[12][2];
  {
    const _Float16* tp = Tb + ((((size_t)b * NCH_ + ch) * 24 + dt) * 32) * 768;
#pragma unroll
    for (int mt = 0; mt < 12; ++mt) {
      const int h = (w * 12 + mt) * 16 + qd * 4;
      const f16x4 c0 = *(const f16x4*)&tp[(size_t)lm * 768 + h];
      const f16x4 c1 = *(const f16x4*)&tp[(size_t)(16 + lm) * 768 + h];
#pragma unroll
      for (int r = 0; r < 4; ++r) {
        acc[mt][0][r] = (float)c0[r];
        acc[mt][1][r] = (float)c1[r];
      }
    }
  }

  const size_t ktb = (size_t)b * H_ * S_;
  const size_t vrow0 = ktb + (size_t)(d0 + lm) * S_;
  const size_t vrow1 = ktb + (size_t)(d0 + 16 + lm) * S_;

  for (int blk = ch * LCH_; blk < ch * LCH_ + LCH_; ++blk) {
    const int s0 = blk * 64;
    // ---- update: St = St*a + K^T V ----
    f16x8 vf00 = *(const f16x8*)&VT[vrow0 + s0 + qd * 8];
    f16x8 vf01 = *(const f16x8*)&VT[vrow0 + s0 + 32 + qd * 8];
    f16x8 vf10 = *(const f16x8*)&VT[vrow1 + s0 + qd * 8];
    f16x8 vf11 = *(const f16x8*)&VT[vrow1 + s0 + 32 + qd * 8];
#pragma unroll
    for (int mt = 0; mt < 12; ++mt) {
      const size_t arow = ktb + (size_t)((w * 12 + mt) * 16 + lm) * S_ + s0 + qd * 8;
      f16x8 a0 = *(const f16x8*)&KT[arow];
      f16x8 a1 = *(const f16x8*)&KT[arow + 32];
      f32x4 c0 = acc[mt][0] * av0;
      f32x4 c1 = acc[mt][1] * av1;
      c0 = __builtin_amdgcn_mfma_f32_16x16x32_f16(a0, vf00, c0, 0, 0, 0);
      c0 = __builtin_amdgcn_mfma_f32_16x16x32_f16(a1, vf01, c0, 0, 0, 0);
      c1 = __builtin_amdgcn_mfma_f32_16x16x32_f16(a0, vf10, c1, 0, 0, 0);
      c1 = __builtin_amdgcn_mfma_f32_16x16x32_f16(a1, vf11, c1, 0, 0, 0);
      acc[mt][0] = c0;
      acc[mt][1] = c1;
    }
    __syncthreads();   // previous step's StL readers done
    // ---- St -> LDS f16, layout StL[d][h] ----
#pragma unroll
    for (int mt = 0; mt < 12; ++mt) {
      const int h = (w * 12 + mt) * 16 + qd * 4;
      f16x4 p0, p1;
#pragma unroll
      for (int r = 0; r < 4; ++r) {
        p0[r] = (_Float16)acc[mt][0][r];
        p1[r] = (_Float16)acc[mt][1][r];
      }
      *(f16x4*)&StL[lm * STP + h] = p0;
      *(f16x4*)&StL[(16 + lm) * STP + h] = p1;
    }
    __syncthreads();
    // ---- output: O += Q . St (wave w owns rows s0 + w*16 .. +15) ----
    f32x4 o0a = {0.f,0.f,0.f,0.f}, o0b = {0.f,0.f,0.f,0.f};
    f32x4 o1a = {0.f,0.f,0.f,0.f}, o1b = {0.f,0.f,0.f,0.f};
    const size_t qrow = ((size_t)b * S_ + s0 + w * 16 + lm) * H_ + qd * 8;
#pragma unroll 3
    for (int kt = 0; kt < 24; kt += 2) {
      f16x8 qa = *(const f16x8*)&Qb[qrow + kt * 32];
      f16x8 qb2 = *(const f16x8*)&Qb[qrow + kt * 32 + 32];
      f16x8 s00 = *(f16x8*)&StL[lm * STP + kt * 32 + qd * 8];
      f16x8 s01 = *(f16x8*)&StL[(16 + lm) * STP + kt * 32 + qd * 8];
      f16x8 s10 = *(f16x8*)&StL[lm * STP + kt * 32 + 32 + qd * 8];
      f16x8 s11 = *(f16x8*)&StL[(16 + lm) * STP + kt * 32 + 32 + qd * 8];
      o0a = __builtin_amdgcn_mfma_f32_16x16x32_f16(qa, s00, o0a, 0, 0, 0);
      o1a = __builtin_amdgcn_mfma_f32_16x16x32_f16(qa, s01, o1a, 0, 0, 0);
      o0b = __builtin_amdgcn_mfma_f32_16x16x32_f16(qb2, s10, o0b, 0, 0, 0);
      o1b = __builtin_amdgcn_mfma_f32_16x16x32_f16(qb2, s11, o1b, 0, 0, 0);
    }
    const f32x4 o0 = o0a + o0b;
    const f32x4 o1 = o1a + o1b;
    const size_t orow = ((size_t)b * S_ + s0 + w * 16 + qd * 4) * H_ + d0;
#pragma unroll
    for (int r = 0; r < 4; ++r) {
      O[orow + (size_t)r * H_ + lm] += o0[r];
      O[orow + (size_t)r * H_ + 16 + lm] += o1[r];
    }
  }
}

// ---------------------------------------------------------------------------
extern "C" void kernel_launch(void* const* d_in, const int* in_sizes, int n_in,
                              void* d_out, int out_size, void* d_ws, size_t ws_size,
                              hipStream_t stream) {
  (void)in_sizes; (void)n_in; (void)out_size; (void)ws_size;
  const float* x    = (const float*)d_in[0];
  const float* Wq   = (const float*)d_in[1];
  const float* Wk   = (const float*)d_in[2];
  const float* Wv   = (const float*)d_in[3];
  const float* W1   = (const float*)d_in[4];
  const float* W2   = (const float*)d_in[5];
  const float* bias = (const float*)d_in[6];
  float* O = (float*)d_out;

  // workspace (~221 MiB; proven available >= ~307 MiB):
  // Qb row-major f16; KT,VT transposed f16; weightsT; tbuf; abuf; Tb
  char* ws = (char*)d_ws;
  _Float16* Qb  = (_Float16*)ws;
  _Float16* KT  = Qb + (size_t)M_ * H_;
  _Float16* VT  = KT + (size_t)M_ * H_;
  _Float16* WqT = VT + (size_t)M_ * H_;
  _Float16* WkT = WqT + H_ * H_;
  _Float16* WvT = WkT + H_ * H_;
  float* tbuf = (float*)(WvT + H_ * H_);
  float* abuf = tbuf + (size_t)M_ * 16;
  _Float16* Tb = (_Float16*)(abuf + B_ * H_);   // [b][ch][d=768][h=768]

  k_transpose<<<dim3(24, 24), 256, 0, stream>>>(Wq, WqT);
  k_transpose<<<dim3(24, 24), 256, 0, stream>>>(Wk, WkT);
  k_transpose<<<dim3(24, 24), 256, 0, stream>>>(Wv, WvT);
  k_tgemm<<<dim3(512), 256, 0, stream>>>(x, W1, tbuf);
  k_areduce<<<dim3(24, 8), 256, 0, stream>>>(tbuf, W2, bias, abuf);
  k_gemm_qkv<<<dim3(512, 6), 256, 0, stream>>>(x, WqT, WkT, WvT, Qb, KT, VT);
  k_scores_y<<<dim3(64, 8), 256, 0, stream>>>(Qb, KT, VT, O);
  k_chunk_gemm<<<dim3(288, 8), 256, 0, stream>>>(KT, VT, abuf, Tb);
  k_combine<<<dim3(2304), 256, 0, stream>>>(abuf, Tb);
  k_scan_out<<<dim3(1536), 256, 0, stream>>>(Qb, KT, VT, abuf, Tb, O);
}

// Round 7
// 1273.203 us; speedup vs baseline: 1.2025x; 1.0133x over previous
//
#include <hip/hip_runtime.h>

#define B_ 8
#define S_ 4096
#define H_ 768
#define C_ 64
#define NB_ 64
#define M_ (B_*S_)   // 32768 rows

#define NCH_ 8       // scan chunks
#define LCH_ 8       // blocks per chunk (NB_/NCH_)

typedef _Float16 f16x8 __attribute__((ext_vector_type(8)));
typedef _Float16 f16x4 __attribute__((ext_vector_type(4)));
typedef float    f32x4 __attribute__((ext_vector_type(4)));

// ---------------------------------------------------------------------------
// Weight transpose + f16 cast: WT[n][k] = (f16) W[k][n]
// ---------------------------------------------------------------------------
__global__ __launch_bounds__(256) void k_transpose(const float* __restrict__ src,
                                                   _Float16* __restrict__ dst) {
  __shared__ float tile[32][33];
  const int t = threadIdx.x;
  const int tx = t & 31, ty = t >> 5;              // ty 0..7
  const int n0 = blockIdx.x * 32, k0 = blockIdx.y * 32;
#pragma unroll
  for (int i = 0; i < 4; ++i)
    tile[ty + i*8][tx] = src[(k0 + ty + i*8) * H_ + n0 + tx];
  __syncthreads();
#pragma unroll
  for (int i = 0; i < 4; ++i)
    dst[(n0 + ty + i*8) * H_ + k0 + tx] = (_Float16)tile[tx][ty + i*8];
}

// ---------------------------------------------------------------------------
// Fused Q/K/V GEMM (f16 MFMA 16x16x32). Tile 64(M) x 128(N), 256 threads.
// Writes: Qb[s][h], Kb[s][h] (row-major) and KT[b][h][s], VT[b][d][s]
// (transposed, packed f16x4 along s).
// ---------------------------------------------------------------------------
__global__ __launch_bounds__(256) void k_gemm_qkv(
    const float* __restrict__ x,
    const _Float16* __restrict__ WqT, const _Float16* __restrict__ WkT,
    const _Float16* __restrict__ WvT,
    _Float16* __restrict__ Qb, _Float16* __restrict__ Kb,
    _Float16* __restrict__ KT, _Float16* __restrict__ VT) {
  __shared__ _Float16 xs[64][40];        // [m][k]
  __shared__ _Float16 ws[3][128][40];    // [mat][n][k]
  const int t = threadIdx.x;
  const int m0 = blockIdx.x * 64, n0 = blockIdx.y * 128;
  const int lane = t & 63, wv = t >> 6;
  const int lm = lane & 15, qd = lane >> 4;
  const int sm = t >> 2, sk = (t & 3) * 8;   // x staging
  const int wn = t >> 1, wk = (t & 1) * 16;  // W staging

  f32x4 acc[3][4][2];
#pragma unroll
  for (int a = 0; a < 3; ++a)
#pragma unroll
    for (int i = 0; i < 4; ++i)
#pragma unroll
      for (int n = 0; n < 2; ++n)
        acc[a][i][n] = (f32x4){0.f, 0.f, 0.f, 0.f};

  for (int kk = 0; kk < 24; ++kk) {
    const int k0 = kk * 32;
    __syncthreads();
    { // stage x tile 64x32 (f32 -> f16)
      const f32x4* xp = (const f32x4*)&x[(size_t)(m0 + sm) * H_ + k0 + sk];
      f32x4 f0 = xp[0], f1 = xp[1];
      f16x8 xv;
#pragma unroll
      for (int j = 0; j < 4; ++j) { xv[j] = (_Float16)f0[j]; xv[4 + j] = (_Float16)f1[j]; }
      *(f16x8*)&xs[sm][sk] = xv;
    }
    { // stage 3 W tiles 128x32
      const f16x8* wp = (const f16x8*)&WqT[(n0 + wn) * H_ + k0 + wk];
      *(f16x8*)&ws[0][wn][wk] = wp[0]; *(f16x8*)&ws[0][wn][wk + 8] = wp[1];
      wp = (const f16x8*)&WkT[(n0 + wn) * H_ + k0 + wk];
      *(f16x8*)&ws[1][wn][wk] = wp[0]; *(f16x8*)&ws[1][wn][wk + 8] = wp[1];
      wp = (const f16x8*)&WvT[(n0 + wn) * H_ + k0 + wk];
      *(f16x8*)&ws[2][wn][wk] = wp[0]; *(f16x8*)&ws[2][wn][wk + 8] = wp[1];
    }
    __syncthreads();
    f16x8 af[4];
#pragma unroll
    for (int i = 0; i < 4; ++i) af[i] = *(f16x8*)&xs[i*16 + lm][qd*8];
#pragma unroll
    for (int a = 0; a < 3; ++a)
#pragma unroll
      for (int n = 0; n < 2; ++n) {
        f16x8 bfr = *(f16x8*)&ws[a][wv*32 + n*16 + lm][qd*8];
#pragma unroll
        for (int i = 0; i < 4; ++i)
          acc[a][i][n] = __builtin_amdgcn_mfma_f32_16x16x32_f16(af[i], bfr, acc[a][i][n], 0, 0, 0);
      }
  }
  // epilogue: C row=(lane>>4)*4+r (global s), col=lane&15 (global h/d)
#pragma unroll
  for (int i = 0; i < 4; ++i)
#pragma unroll
    for (int n = 0; n < 2; ++n) {
      const int ng = n0 + wv*32 + n*16 + lm;
      const int mg0 = m0 + i*16 + qd*4;
      const int bb = mg0 >> 12, ss = mg0 & (S_ - 1);
#pragma unroll
      for (int r = 0; r < 4; ++r) {
        Qb[(size_t)(mg0 + r) * H_ + ng] = (_Float16)acc[0][i][n][r];
        Kb[(size_t)(mg0 + r) * H_ + ng] = (_Float16)acc[1][i][n][r];
      }
      f16x4 kp, vp;
#pragma unroll
      for (int r = 0; r < 4; ++r) {
        kp[r] = (_Float16)acc[1][i][n][r];
        vp[r] = (_Float16)acc[2][i][n][r];
      }
      *(f16x4*)&KT[((size_t)bb * H_ + ng) * S_ + ss] = kp;
      *(f16x4*)&VT[((size_t)bb * H_ + ng) * S_ + ss] = vp;
    }
}

// ---------------------------------------------------------------------------
// t = x @ W1   [32768 x 16]
// ---------------------------------------------------------------------------
__global__ __launch_bounds__(256) void k_tgemm(const float* __restrict__ x,
                                               const float* __restrict__ W1,
                                               float* __restrict__ tbuf) {
  __shared__ float w1s[768 * 16];
  __shared__ float xs[64 * 129];
  const int t = threadIdx.x;
  const int m0 = blockIdx.x * 64;
  for (int i = t; i < 768 * 16 / 4; i += 256)
    ((f32x4*)w1s)[i] = ((const f32x4*)W1)[i];
  const int row = t & 63, cg = t >> 6;
  f32x4 acc = (f32x4){0.f, 0.f, 0.f, 0.f};
  for (int kc = 0; kc < 768; kc += 128) {
    __syncthreads();
    for (int i = 0; i < 32; ++i) {
      const int idx = t + 256 * i;
      const int r = idx >> 7, c = idx & 127;
      xs[r * 129 + c] = x[(size_t)(m0 + r) * H_ + kc + c];
    }
    __syncthreads();
#pragma unroll 8
    for (int kl = 0; kl < 128; ++kl) {
      const float a = xs[row * 129 + kl];
      const f32x4 w = *(const f32x4*)&w1s[(kc + kl) * 16 + cg * 4];
#pragma unroll
      for (int j = 0; j < 4; ++j) acc[j] += a * w[j];
    }
  }
  *(f32x4*)&tbuf[(size_t)(m0 + row) * 16 + cg * 4] = acc;
}

// ---------------------------------------------------------------------------
// a[b,h] = mean_s sigmoid((t@W2)[b,s,h] + bias[h]) ^ (1/16)
// ---------------------------------------------------------------------------
__global__ __launch_bounds__(256) void k_areduce(const float* __restrict__ tbuf,
                                                 const float* __restrict__ W2,
                                                 const float* __restrict__ bias,
                                                 float* __restrict__ abuf) {
  __shared__ float ts[128 * 17];
  __shared__ float rbuf[8 * 32];
  const int t = threadIdx.x;
  const int b = blockIdx.y, hc = blockIdx.x;
  const int hl = t & 31, sg = t >> 5;
  const int h = hc * 32 + hl;
  float w2r[16];
#pragma unroll
  for (int j = 0; j < 16; ++j) w2r[j] = W2[j * H_ + h];
  const float bb = bias[h];
  float asum = 0.f;
  const float* tb = &tbuf[(size_t)(b * S_) * 16];
  for (int sc = 0; sc < S_; sc += 128) {
    __syncthreads();
    for (int i = 0; i < 8; ++i) {
      const int idx = t + 256 * i;
      const int sl = idx >> 4, j = idx & 15;
      ts[sl * 17 + j] = tb[(size_t)(sc + sl) * 16 + j];
    }
    __syncthreads();
    for (int i = 0; i < 16; ++i) {
      const int sl = sg + i * 8;
      float z = bb;
      const float* tr = &ts[sl * 17];
#pragma unroll
      for (int j = 0; j < 16; ++j) z += tr[j] * w2r[j];
      const float sgm = 1.f / (1.f + __expf(-z));
      asum += sqrtf(sqrtf(sqrtf(sqrtf(sgm))));  // ^(1/16)
    }
  }
  rbuf[sg * 32 + hl] = asum;
  __syncthreads();
  if (t < 32) {
    float s = 0.f;
#pragma unroll
    for (int g = 0; g < 8; ++g) s += rbuf[g * 32 + t];
    abuf[b * H_ + hc * 32 + t] = s * (1.f / (float)S_);
  }
}

// ---------------------------------------------------------------------------
// Per block (MFMA version): S = Q K^T via mfma, mask*scale -> wb[d][c] (f32),
// proven softmax block (zeros included), P -> f16 pl[c][d], Y = P V via mfma
// with V frags straight from VT. O full overwrite (scan adds on top).
// grid (64 nb, 8 b), 256 threads, 4 waves.
// ---------------------------------------------------------------------------
__global__ __launch_bounds__(256, 2) void k_scores_y(
    const _Float16* __restrict__ Qb, const _Float16* __restrict__ Kb,
    const _Float16* __restrict__ VT, float* __restrict__ O) {
  __shared__ float wb[64 * 68];                    // [d][c] scores^T
  __shared__ __align__(16) _Float16 pl[64 * 72];   // [c][d] P row-major f16
  const int t = threadIdx.x;
  const int nb = blockIdx.x, b = blockIdx.y;
  const int w = t >> 6, lane = t & 63;
  const int lm = lane & 15, qd = lane >> 4;
  const size_t rbase = (size_t)b * S_ + (size_t)nb * 64;

  // ---- S = Q K^T (wave w: rows w*16..+15, all 64 cols) ----
  f32x4 sacc[4];
#pragma unroll
  for (int u = 0; u < 4; ++u) sacc[u] = (f32x4){0.f, 0.f, 0.f, 0.f};
  for (int hk = 0; hk < 24; ++hk) {
    const f16x8 qa = *(const f16x8*)&Qb[(rbase + w * 16 + lm) * H_ + hk * 32 + qd * 8];
#pragma unroll
    for (int u = 0; u < 4; ++u) {
      const f16x8 kb = *(const f16x8*)&Kb[(rbase + u * 16 + lm) * H_ + hk * 32 + qd * 8];
      sacc[u] = __builtin_amdgcn_mfma_f32_16x16x32_f16(qa, kb, sacc[u], 0, 0, 0);
    }
  }
  // mask by multiplication + scale, store S^T -> wb[d][c]
  const float scale = 0.036084391824351615f;  // 1/sqrt(768)
#pragma unroll
  for (int u = 0; u < 4; ++u) {
    const int cp = u * 16 + lm;                 // score col d
    f32x4 m;
#pragma unroll
    for (int r = 0; r < 4; ++r) {
      const int c = w * 16 + qd * 4 + r;        // score row c
      m[r] = (cp <= c) ? sacc[u][r] * scale : 0.f;
    }
    *(f32x4*)&wb[cp * 68 + w * 16 + qd * 4] = m;
  }
  __syncthreads();
  { // softmax over 64-wide rows (zeros included), 4 threads per row (proven)
    const int r = t >> 2, g = t & 3;
    float vals[16];
    float mx = -1e30f;
#pragma unroll
    for (int i = 0; i < 16; ++i) {
      vals[i] = wb[(g * 16 + i) * 68 + r];
      mx = fmaxf(mx, vals[i]);
    }
    mx = fmaxf(mx, __shfl_xor(mx, 1));
    mx = fmaxf(mx, __shfl_xor(mx, 2));
    float sm = 0.f;
#pragma unroll
    for (int i = 0; i < 16; ++i) { vals[i] = __expf(vals[i] - mx); sm += vals[i]; }
    sm += __shfl_xor(sm, 1);
    sm += __shfl_xor(sm, 2);
    const float inv = 1.f / sm;
#pragma unroll
    for (int i = 0; i < 16; ++i)
      pl[r * 72 + g * 16 + i] = (_Float16)(vals[i] * inv);   // P[c][d] f16
  }
  __syncthreads();
  // ---- Y = P V (wave w: all 64 rows, e-range w*192..+191) ----
  f32x4 acc[4][12];
#pragma unroll
  for (int i = 0; i < 4; ++i)
#pragma unroll
    for (int nd = 0; nd < 12; ++nd) acc[i][nd] = (f32x4){0.f, 0.f, 0.f, 0.f};
#pragma unroll
  for (int kk = 0; kk < 2; ++kk) {
    f16x8 sa[4];
#pragma unroll
    for (int i = 0; i < 4; ++i)
      sa[i] = *(const f16x8*)&pl[(i * 16 + lm) * 72 + kk * 32 + qd * 8];
#pragma unroll
    for (int nd = 0; nd < 12; ++nd) {
      const f16x8 vb = *(const f16x8*)&VT[((size_t)b * H_ + w * 192 + nd * 16 + lm) * S_
                                          + nb * 64 + kk * 32 + qd * 8];
#pragma unroll
      for (int i = 0; i < 4; ++i)
        acc[i][nd] = __builtin_amdgcn_mfma_f32_16x16x32_f16(sa[i], vb, acc[i][nd], 0, 0, 0);
    }
  }
  // store O (full overwrite; scan accumulates on top)
#pragma unroll
  for (int i = 0; i < 4; ++i)
#pragma unroll
    for (int nd = 0; nd < 12; ++nd)
#pragma unroll
      for (int r = 0; r < 4; ++r)
        O[(rbase + i * 16 + qd * 4 + r) * H_ + w * 192 + nd * 16 + lm] = acc[i][nd][r];
}

// ---------------------------------------------------------------------------
// Chunk-total GEMM: T^T[d][h] = sum_{s' in chunk} a_d^{LCH-1-m(s')} V[s',d] K[s',h]
// (proven round 4). Tb layout: [b][ch][d=768][h=768] f16.
// grid x = tile*8 + ch (36 tiles of 128x128), y = b. 256 thr, 4 waves.
// ---------------------------------------------------------------------------
__global__ __launch_bounds__(256, 2) void k_chunk_gemm(
    const _Float16* __restrict__ KT, const _Float16* __restrict__ VT,
    const float* __restrict__ abuf, _Float16* __restrict__ Tb) {
  __shared__ _Float16 bs[128][40];   // K tile [h_local][s'_local], all waves
  const int t = threadIdx.x;
  const int b = blockIdx.y;
  const int ch = blockIdx.x & 7, tile = blockIdx.x >> 3;
  const int dt = tile / 6, ht = tile % 6;
  const int w = t >> 6, lane = t & 63;
  const int lm = lane & 15, qd = lane >> 4;
  const int d0 = dt * 128 + w * 32;
  const int h0 = ht * 128;
  const int hrow = t >> 1, hseg = (t & 1) * 16;

  float av[2], pw[2];
  av[0] = abuf[b * H_ + d0 + lm];
  av[1] = abuf[b * H_ + d0 + 16 + lm];
  pw[0] = 1.f; pw[1] = 1.f;

  f32x4 acc[2][8];
#pragma unroll
  for (int ds = 0; ds < 2; ++ds)
#pragma unroll
    for (int hh = 0; hh < 8; ++hh) acc[ds][hh] = (f32x4){0.f, 0.f, 0.f, 0.f};

  const size_t ktb = (size_t)b * H_ * S_;
  for (int kk = 15; kk >= 0; --kk) {
    const int sp = ch * 512 + kk * 32;
    __syncthreads();
    { // stage K tile [128 h][32 s'] (KT rows are contiguous in s)
      const f16x8* kp = (const f16x8*)&KT[ktb + (size_t)(h0 + hrow) * S_ + sp + hseg];
      *(f16x8*)&bs[hrow][hseg] = kp[0];
      *(f16x8*)&bs[hrow][hseg + 8] = kp[1];
    }
    __syncthreads();
    f16x8 va0 = *(const f16x8*)&VT[ktb + (size_t)(d0 + lm) * S_ + sp + qd * 8];
    f16x8 va1 = *(const f16x8*)&VT[ktb + (size_t)(d0 + 16 + lm) * S_ + sp + qd * 8];
    va0 *= (_Float16)pw[0];
    va1 *= (_Float16)pw[1];
#pragma unroll
    for (int hh = 0; hh < 8; ++hh) {
      const f16x8 kf = *(const f16x8*)&bs[hh * 16 + lm][qd * 8];
      acc[0][hh] = __builtin_amdgcn_mfma_f32_16x16x32_f16(va0, kf, acc[0][hh], 0, 0, 0);
      acc[1][hh] = __builtin_amdgcn_mfma_f32_16x16x32_f16(va1, kf, acc[1][hh], 0, 0, 0);
    }
    if (!(kk & 1)) { pw[0] *= av[0]; pw[1] *= av[1]; }
  }
  // store T^T[d][h]: C row=(lane>>4)*4+r -> d_local, col=lane&15 -> h_local
  _Float16* tp = Tb + (size_t)(b * NCH_ + ch) * 768 * 768;
#pragma unroll
  for (int ds = 0; ds < 2; ++ds)
#pragma unroll
    for (int hh = 0; hh < 8; ++hh)
#pragma unroll
      for (int r = 0; r < 4; ++r)
        tp[(size_t)(d0 + ds * 16 + qd * 4 + r) * 768 + h0 + hh * 16 + lm] =
            (_Float16)acc[ds][hh][r];
}

// ---------------------------------------------------------------------------
// Chunk-carry combine (in place): Cin_0 = 0; Cin_p = a^LCH * Cin_{p-1} + T_{p-1}.
// Each thread owns one f16x8 strip (8 h) across all chunks, carry in f32.
// grid 2304 x 256 = 8b * 24dt * 32dl * 96hv threads. (proven)
// ---------------------------------------------------------------------------
__global__ __launch_bounds__(256) void k_combine(const float* __restrict__ abuf,
                                                 _Float16* __restrict__ Tb) {
  const int gid = blockIdx.x * 256 + threadIdx.x;
  const int hv = gid % 96;
  const int dl = (gid / 96) & 31;
  const int dt = (gid / (96 * 32)) % 24;
  const int b  = gid / (96 * 32 * 24);
  const float ad = abuf[b * H_ + dt * 32 + dl];
  const float a2 = ad * ad, a4 = a2 * a2;
  const float aL = a4 * a4;  // a^8 == a^LCH_
  float carry[8];
#pragma unroll
  for (int j = 0; j < 8; ++j) carry[j] = 0.f;
  const size_t chstride = (size_t)24 * 32 * 768;
  _Float16* p = Tb + (size_t)b * NCH_ * chstride + ((size_t)dt * 32 + dl) * 768 + hv * 8;
  for (int ch = 0; ch < NCH_; ++ch, p += chstride) {
    const f16x8 tv = *(const f16x8*)p;
    f16x8 cv;
#pragma unroll
    for (int j = 0; j < 8; ++j) {
      cv[j] = (_Float16)carry[j];
      carry[j] = carry[j] * aL + (float)tv[j];
    }
    *(f16x8*)p = cv;
  }
}

// ---------------------------------------------------------------------------
// Chunked scan phase 3 (proven body, d-tile 32) + XCD-grouping swizzle
// (proven round 6: FETCH -3x). grid flat 1536, 256 threads (4 waves).
// ---------------------------------------------------------------------------
#define STP 776  // StL h-stride (halves): 16B aligned, 2-way-free banks
__global__ __launch_bounds__(256, 2) void k_scan_out(
    const _Float16* __restrict__ Qb, const _Float16* __restrict__ KT,
    const _Float16* __restrict__ VT, const float* __restrict__ abuf,
    const _Float16* __restrict__ Tb, float* __restrict__ O) {
  __shared__ _Float16 StL[32 * STP];
  const int t = threadIdx.x;
  // XCD-group decode: lin%8 = xcd slot; groups g=(j/24)*8+xcd, dt=j%24
  const int lin = blockIdx.x;
  const int xcd = lin & 7, j = lin >> 3;
  const int g = (j / 24) * 8 + xcd;           // 0..63 = (b,ch) group
  const int dt = j % 24;
  const int ch = g & 7, b = g >> 3;
  const int d0 = dt * 32;
  const int w = t >> 6, lane = t & 63;
  const int lm = lane & 15, qd = lane >> 4;

  const float av0 = abuf[b * H_ + d0 + lm];
  const float av1 = abuf[b * H_ + d0 + 16 + lm];

  // init state from carry-in
  f32x4 acc[12][2];
  {
    const _Float16* tp = Tb + ((((size_t)b * NCH_ + ch) * 24 + dt) * 32) * 768;
#pragma unroll
    for (int mt = 0; mt < 12; ++mt) {
      const int h = (w * 12 + mt) * 16 + qd * 4;
      const f16x4 c0 = *(const f16x4*)&tp[(size_t)lm * 768 + h];
      const f16x4 c1 = *(const f16x4*)&tp[(size_t)(16 + lm) * 768 + h];
#pragma unroll
      for (int r = 0; r < 4; ++r) {
        acc[mt][0][r] = (float)c0[r];
        acc[mt][1][r] = (float)c1[r];
      }
    }
  }

  const size_t ktb = (size_t)b * H_ * S_;
  const size_t vrow0 = ktb + (size_t)(d0 + lm) * S_;
  const size_t vrow1 = ktb + (size_t)(d0 + 16 + lm) * S_;

  for (int blk = ch * LCH_; blk < ch * LCH_ + LCH_; ++blk) {
    const int s0 = blk * 64;
    // ---- update: St = St*a + K^T V ----
    f16x8 vf00 = *(const f16x8*)&VT[vrow0 + s0 + qd * 8];
    f16x8 vf01 = *(const f16x8*)&VT[vrow0 + s0 + 32 + qd * 8];
    f16x8 vf10 = *(const f16x8*)&VT[vrow1 + s0 + qd * 8];
    f16x8 vf11 = *(const f16x8*)&VT[vrow1 + s0 + 32 + qd * 8];
#pragma unroll
    for (int mt = 0; mt < 12; ++mt) {
      const size_t arow = ktb + (size_t)((w * 12 + mt) * 16 + lm) * S_ + s0 + qd * 8;
      f16x8 a0 = *(const f16x8*)&KT[arow];
      f16x8 a1 = *(const f16x8*)&KT[arow + 32];
      f32x4 c0 = acc[mt][0] * av0;
      f32x4 c1 = acc[mt][1] * av1;
      c0 = __builtin_amdgcn_mfma_f32_16x16x32_f16(a0, vf00, c0, 0, 0, 0);
      c0 = __builtin_amdgcn_mfma_f32_16x16x32_f16(a1, vf01, c0, 0, 0, 0);
      c1 = __builtin_amdgcn_mfma_f32_16x16x32_f16(a0, vf10, c1, 0, 0, 0);
      c1 = __builtin_amdgcn_mfma_f32_16x16x32_f16(a1, vf11, c1, 0, 0, 0);
      acc[mt][0] = c0;
      acc[mt][1] = c1;
    }
    __syncthreads();   // previous step's StL readers done
    // ---- St -> LDS f16, layout StL[d][h] ----
#pragma unroll
    for (int mt = 0; mt < 12; ++mt) {
      const int h = (w * 12 + mt) * 16 + qd * 4;
      f16x4 p0, p1;
#pragma unroll
      for (int r = 0; r < 4; ++r) {
        p0[r] = (_Float16)acc[mt][0][r];
        p1[r] = (_Float16)acc[mt][1][r];
      }
      *(f16x4*)&StL[lm * STP + h] = p0;
      *(f16x4*)&StL[(16 + lm) * STP + h] = p1;
    }
    __syncthreads();
    // ---- output: O += Q . St (wave w owns rows s0 + w*16 .. +15) ----
    f32x4 o0a = {0.f,0.f,0.f,0.f}, o0b = {0.f,0.f,0.f,0.f};
    f32x4 o1a = {0.f,0.f,0.f,0.f}, o1b = {0.f,0.f,0.f,0.f};
    const size_t qrow = ((size_t)b * S_ + s0 + w * 16 + lm) * H_ + qd * 8;
#pragma unroll 3
    for (int kt = 0; kt < 24; kt += 2) {
      f16x8 qa = *(const f16x8*)&Qb[qrow + kt * 32];
      f16x8 qb2 = *(const f16x8*)&Qb[qrow + kt * 32 + 32];
      f16x8 s00 = *(f16x8*)&StL[lm * STP + kt * 32 + qd * 8];
      f16x8 s01 = *(f16x8*)&StL[(16 + lm) * STP + kt * 32 + qd * 8];
      f16x8 s10 = *(f16x8*)&StL[lm * STP + kt * 32 + 32 + qd * 8];
      f16x8 s11 = *(f16x8*)&StL[(16 + lm) * STP + kt * 32 + 32 + qd * 8];
      o0a = __builtin_amdgcn_mfma_f32_16x16x32_f16(qa, s00, o0a, 0, 0, 0);
      o1a = __builtin_amdgcn_mfma_f32_16x16x32_f16(qa, s01, o1a, 0, 0, 0);
      o0b = __builtin_amdgcn_mfma_f32_16x16x32_f16(qb2, s10, o0b, 0, 0, 0);
      o1b = __builtin_amdgcn_mfma_f32_16x16x32_f16(qb2, s11, o1b, 0, 0, 0);
    }
    const f32x4 o0 = o0a + o0b;
    const f32x4 o1 = o1a + o1b;
    const size_t orow = ((size_t)b * S_ + s0 + w * 16 + qd * 4) * H_ + d0;
#pragma unroll
    for (int r = 0; r < 4; ++r) {
      O[orow + (size_t)r * H_ + lm] += o0[r];
      O[orow + (size_t)r * H_ + 16 + lm] += o1[r];
    }
  }
}

// ---------------------------------------------------------------------------
extern "C" void kernel_launch(void* const* d_in, const int* in_sizes, int n_in,
                              void* d_out, int out_size, void* d_ws, size_t ws_size,
                              hipStream_t stream) {
  (void)in_sizes; (void)n_in; (void)out_size; (void)ws_size;
  const float* x    = (const float*)d_in[0];
  const float* Wq   = (const float*)d_in[1];
  const float* Wk   = (const float*)d_in[2];
  const float* Wv   = (const float*)d_in[3];
  const float* W1   = (const float*)d_in[4];
  const float* W2   = (const float*)d_in[5];
  const float* bias = (const float*)d_in[6];
  float* O = (float*)d_out;

  // workspace (~282 MiB; proven available >= ~307 MiB):
  // Qb,Kb row-major f16; KT,VT transposed f16; weightsT; tbuf; abuf; Tb
  char* ws = (char*)d_ws;
  _Float16* Qb  = (_Float16*)ws;
  _Float16* Kb  = Qb + (size_t)M_ * H_;
  _Float16* KT  = Kb + (size_t)M_ * H_;
  _Float16* VT  = KT + (size_t)M_ * H_;
  _Float16* WqT = VT + (size_t)M_ * H_;
  _Float16* WkT = WqT + H_ * H_;
  _Float16* WvT = WkT + H_ * H_;
  float* tbuf = (float*)(WvT + H_ * H_);
  float* abuf = tbuf + (size_t)M_ * 16;
  _Float16* Tb = (_Float16*)(abuf + B_ * H_);   // [b][ch][d=768][h=768]

  k_transpose<<<dim3(24, 24), 256, 0, stream>>>(Wq, WqT);
  k_transpose<<<dim3(24, 24), 256, 0, stream>>>(Wk, WkT);
  k_transpose<<<dim3(24, 24), 256, 0, stream>>>(Wv, WvT);
  k_tgemm<<<dim3(512), 256, 0, stream>>>(x, W1, tbuf);
  k_areduce<<<dim3(24, 8), 256, 0, stream>>>(tbuf, W2, bias, abuf);
  k_gemm_qkv<<<dim3(512, 6), 256, 0, stream>>>(x, WqT, WkT, WvT, Qb, Kb, KT, VT);
  k_scores_y<<<dim3(64, 8), 256, 0, stream>>>(Qb, Kb, VT, O);
  k_chunk_gemm<<<dim3(288, 8), 256, 0, stream>>>(KT, VT, abuf, Tb);
  k_combine<<<dim3(2304), 256, 0, stream>>>(abuf, Tb);
  k_scan_out<<<dim3(1536), 256, 0, stream>>>(Qb, KT, VT, abuf, Tb, O);
}